// Round 1
// baseline (10.051 us; speedup 1.0000x reference)
//
#include <hip/hip_runtime.h>

// out[b*H + h] = in[b*C*H + idx[b]*H + h]
// B=4096, C=128, H=256, fp32. One thread per float4 (4 floats).
// H/4 = 64 float4 per row; total B*64 = 262144 threads.

__global__ __launch_bounds__(256) void gather_rows_kernel(
    const float4* __restrict__ in,   // [B, C, H/4] as float4
    const int*    __restrict__ idx,  // [B]
    float4*       __restrict__ out,  // [B, H/4] as float4
    int C, int Hq)                   // Hq = H/4
{
    int tid = blockIdx.x * blockDim.x + threadIdx.x;
    int b = tid / 64;   // Hq == 64
    int j = tid & 63;
    int c = idx[b];
    out[b * Hq + j] = in[(size_t)b * C * Hq + (size_t)c * Hq + j];
}

extern "C" void kernel_launch(void* const* d_in, const int* in_sizes, int n_in,
                              void* d_out, int out_size, void* d_ws, size_t ws_size,
                              hipStream_t stream) {
    const float4* in  = (const float4*)d_in[0];
    const int*    idx = (const int*)d_in[1];
    float4*       out = (float4*)d_out;

    const int B  = in_sizes[1];            // 4096
    const int H  = out_size / B;           // 256
    const int Hq = H / 4;                  // 64
    const int C  = in_sizes[0] / (B * H);  // 128

    const int total  = B * Hq;             // 262144
    const int block  = 256;
    const int grid   = (total + block - 1) / block;

    gather_rows_kernel<<<grid, block, 0, stream>>>(in, idx, out, C, Hq);
}